// Round 5
// baseline (108.844 us; speedup 1.0000x reference)
//
#include <hip/hip_runtime.h>

// MorphoMLP: y = relu(maxplus(relu(maxplus(x,W1)), W2)), fp32.
// B=512, IN=512, HID=1024, OUT=512.
// R7: barrier-free morpho (m233: 2-phase stage/barrier structure is ~70% of
//     critical path; R2/R5/R6 tied at ~95us across occupancy/VALU/LDS knobs,
//     implicating the invariant phase structure, not the pipes).
//   - W-operand stripe (128j x 64k = 32KB) staged into LDS ONCE per block,
//     one barrier total; k-loop has no ds_write, no barrier, no vmcnt drain.
//   - A-operand streamed per-k from global (L2-resident), compiler-pipelined.
//   - 4j x 8b frags/thread: 1.0 VALU instr/update (pk_add f32x2 + v_max3);
//     VALU is the heaviest pipe in the model (128 cyc/k/CU vs LDS 96).
//   - M1: z=8; M2 role-swapped (stripe=A2, stream=W2T) z=16 -> yp[z][b][o],
//     combine needs no transpose. 512 blocks (2/CU) each.
// ws: xT 1MB | W1T 2MB | W2T 2MB | hp 16MB | A2 2MB | yp 16MB = 39MB

#define WS_XT   0                          // [512][512]    x^T  [k][b]
#define WS_W1T  (512 * 512)                // [512][1024]   W1^T [k][j]
#define WS_W2T  (WS_W1T + 512 * 1024)      // [1024][512]   W2^T [k2][o]
#define WS_HP   (WS_W2T + 1024 * 512)      // [8][1024][512]  L1 partials [z][j][b]
#define WS_A2   (WS_HP + 8 * 1024 * 512)   // [1024][512]   relu(h)^T [k2][b]
#define WS_YP   (WS_A2 + 1024 * 512)       // [16][512][512]  L2 partials [z][b][o]

typedef float f32x2 __attribute__((ext_vector_type(2)));

__device__ __forceinline__ float4 fmax4(float4 a, float4 b) {
    return make_float4(fmaxf(a.x, b.x), fmaxf(a.y, b.y),
                       fmaxf(a.z, b.z), fmaxf(a.w, b.w));
}

// ---------------------------------------------------------------------------
// Fused transpose of x (512x512), W1 (1024x512), W2 (512x1024) into ws.
__global__ __launch_bounds__(256) void transpose3(const float* __restrict__ x,
                                                  const float* __restrict__ W1,
                                                  const float* __restrict__ W2,
                                                  float* __restrict__ ws) {
    __shared__ float t[32][33];
    const int id = blockIdx.x;
    const float* src;
    float* dst;
    int R, C, rt, ct;
    if (id < 256) {
        src = x;  dst = ws + WS_XT;  R = 512;  C = 512;
        rt = id >> 4;          ct = id & 15;
    } else if (id < 768) {
        int b = id - 256;
        src = W1; dst = ws + WS_W1T; R = 1024; C = 512;
        rt = b >> 4;           ct = b & 15;
    } else {
        int b = id - 768;
        src = W2; dst = ws + WS_W2T; R = 512;  C = 1024;
        rt = b >> 5;           ct = b & 31;
    }
    const int tx = threadIdx.x & 31, ty = threadIdx.x >> 5;
    const int r0 = rt * 32, c0 = ct * 32;
#pragma unroll
    for (int r = 0; r < 4; r++)
        t[ty + 8 * r][tx] = src[(size_t)(r0 + ty + 8 * r) * C + c0 + tx];
    __syncthreads();
#pragma unroll
    for (int r = 0; r < 4; r++)
        dst[(size_t)(c0 + ty + 8 * r) * R + r0 + tx] = t[tx][ty + 8 * r];
}

// ---------------------------------------------------------------------------
// Barrier-free max-plus tile kernel.
// W-role: [K][JDIM] K-major — a 128-wide j-stripe x KPER k staged once in LDS.
// A-role: [K][512] K-major — streamed from global per k (L2-resident).
// Block tile: 128 j x 64 b x KPER k. 256 threads = 32 ty (4 j each) x 8 tx
// (8 b each). acc init 0 folds the downstream relu.
// Stores raw partial: P[z][j][b] (f4 over b, coalesced).
template <int JDIM, int KPER>
__global__ __launch_bounds__(256, 2) void morphoS(const float* __restrict__ A,
                                                  const float* __restrict__ W,
                                                  float* __restrict__ P) {
    __shared__ float lW[KPER * 128];     // [k][j-stripe] 32KB @ KPER=64
    const int t  = threadIdx.x;
    const int tx = t & 7;                // b frag: b0 + tx*8 + {0..7}
    const int ty = t >> 3;               // j frag: j0 + ty*4 + {0..3}
    const int j0 = blockIdx.x * 128;
    const int b0 = blockIdx.y * 64;
    const int k0 = blockIdx.z * KPER;

    // ---- stage W stripe ONCE: KPER*32 float4, coalesced ----
    const float4* W4 = (const float4*)(W + (size_t)k0 * JDIM) + (j0 >> 2);
    constexpr int NF4 = KPER * 32;       // 32 f4 per 128-float row
#pragma unroll
    for (int q = t; q < NF4; q += 256)
        ((float4*)lW)[q] = W4[(size_t)(q >> 5) * (JDIM / 4) + (q & 31)];
    __syncthreads();                     // the ONLY barrier

    float acc[4][8];                     // [j][b], init 0 == relu fold
#pragma unroll
    for (int jj = 0; jj < 4; jj++)
#pragma unroll
        for (int i = 0; i < 8; i++) acc[jj][i] = 0.0f;

    const float4* A4  = (const float4*)(A + (size_t)k0 * 512) + (b0 >> 2) + tx * 2;
    const float4* lW4 = (const float4*)lW;

    // ---- k-loop: no barriers, no LDS writes; A from L2, W from LDS ----
#pragma unroll 2
    for (int k = 0; k < KPER; k += 2) {
        const float4 a00 = A4[(size_t)k * 128];          // k,   b lo
        const float4 a01 = A4[(size_t)k * 128 + 1];      // k,   b hi
        const float4 a10 = A4[(size_t)(k + 1) * 128];    // k+1, b lo
        const float4 a11 = A4[(size_t)(k + 1) * 128 + 1];// k+1, b hi
        const float4 w0  = lW4[k * 32 + ty];             // k,   j frag
        const float4 w1  = lW4[(k + 1) * 32 + ty];       // k+1, j frag

        const f32x2 a00p0 = {a00.x, a00.y}, a00p1 = {a00.z, a00.w};
        const f32x2 a01p0 = {a01.x, a01.y}, a01p1 = {a01.z, a01.w};
        const f32x2 a10p0 = {a10.x, a10.y}, a10p1 = {a10.z, a10.w};
        const f32x2 a11p0 = {a11.x, a11.y}, a11p1 = {a11.z, a11.w};

#define UPDJ(JR, W0C, W1C)                                                  \
    {                                                                       \
        const f32x2 wa = {(W0C), (W0C)};                                    \
        const f32x2 wb = {(W1C), (W1C)};                                    \
        const f32x2 s0 = a00p0 + wa, u0 = a10p0 + wb;                       \
        const f32x2 s1 = a00p1 + wa, u1 = a10p1 + wb;                       \
        const f32x2 s2 = a01p0 + wa, u2 = a11p0 + wb;                       \
        const f32x2 s3 = a01p1 + wa, u3 = a11p1 + wb;                       \
        acc[JR][0] = fmaxf(fmaxf(acc[JR][0], s0.x), u0.x);                  \
        acc[JR][1] = fmaxf(fmaxf(acc[JR][1], s0.y), u0.y);                  \
        acc[JR][2] = fmaxf(fmaxf(acc[JR][2], s1.x), u1.x);                  \
        acc[JR][3] = fmaxf(fmaxf(acc[JR][3], s1.y), u1.y);                  \
        acc[JR][4] = fmaxf(fmaxf(acc[JR][4], s2.x), u2.x);                  \
        acc[JR][5] = fmaxf(fmaxf(acc[JR][5], s2.y), u2.y);                  \
        acc[JR][6] = fmaxf(fmaxf(acc[JR][6], s3.x), u3.x);                  \
        acc[JR][7] = fmaxf(fmaxf(acc[JR][7], s3.y), u3.y);                  \
    }
        UPDJ(0, w0.x, w1.x)
        UPDJ(1, w0.y, w1.y)
        UPDJ(2, w0.z, w1.z)
        UPDJ(3, w0.w, w1.w)
#undef UPDJ
    }

    // ---- store partial: P[z][j][b], 2 f4 per j-row, coalesced over tx ----
    float* Pp = P + (size_t)blockIdx.z * JDIM * 512;
#pragma unroll
    for (int jj = 0; jj < 4; jj++) {
        float* row = Pp + (size_t)(j0 + ty * 4 + jj) * 512 + b0 + tx * 8;
        *(float4*)(row)     = make_float4(acc[jj][0], acc[jj][1], acc[jj][2], acc[jj][3]);
        *(float4*)(row + 4) = make_float4(acc[jj][4], acc[jj][5], acc[jj][6], acc[jj][7]);
    }
}

// ---------------------------------------------------------------------------
// combineH: A2[j][b] = relu(max_z hp[z][j][b]).  K-major input for M2 stripe.
// 512 blocks x 256 thr x 1 float4 = 512K floats.
__global__ __launch_bounds__(256) void combineH(const float* __restrict__ hp,
                                                float* __restrict__ A2) {
    const int i = blockIdx.x * 256 + threadIdx.x;   // float4 index
    const float4* p = (const float4*)hp;
    float4 m = p[i];
#pragma unroll
    for (int z = 1; z < 8; z++) m = fmax4(m, p[i + z * 131072]);  // 512K floats/4
    m = fmax4(m, make_float4(0.f, 0.f, 0.f, 0.f));
    ((float4*)A2)[i] = m;
}

// ---------------------------------------------------------------------------
// combineY: out[b][o] = max_z yp[z][b][o] — partials already relu-clamped
// (acc init 0) and already in [b][o] layout. Pure coalesced f4 max.
// 256 blocks x 256 thr x 1 float4 = 256K floats.
__global__ __launch_bounds__(256) void combineY2(const float* __restrict__ yp,
                                                 float* __restrict__ out) {
    const int i = blockIdx.x * 256 + threadIdx.x;   // float4 index
    const float4* p = (const float4*)yp;
    float4 m = p[i];
#pragma unroll
    for (int z = 1; z < 16; z++) m = fmax4(m, p[i + z * 65536]);  // 256K floats/4
    ((float4*)out)[i] = m;
}

// ---------------------------------------------------------------------------
extern "C" void kernel_launch(void* const* d_in, const int* in_sizes, int n_in,
                              void* d_out, int out_size, void* d_ws, size_t ws_size,
                              hipStream_t stream) {
    (void)in_sizes; (void)n_in; (void)out_size; (void)ws_size;
    const float* x  = (const float*)d_in[0];
    const float* W1 = (const float*)d_in[1];
    const float* W2 = (const float*)d_in[2];
    float* ws  = (float*)d_ws;
    float* out = (float*)d_out;

    // 1) K-major transposes of x, W1, W2
    transpose3<<<1280, 256, 0, stream>>>(x, W1, W2, ws);

    // 2) L1: stripe = W1T (j), stream = xT (b). hp[8][1024][512].
    //    grid 8(j) x 8(b) x 8(z), KPER=64 -> 512 blocks, 2/CU.
    morphoS<1024, 64><<<dim3(8, 8, 8), 256, 0, stream>>>(
        ws + WS_XT, ws + WS_W1T, ws + WS_HP);

    // 3) combine 8 partials + relu -> A2[k2][b]
    combineH<<<512, 256, 0, stream>>>(ws + WS_HP, ws + WS_A2);

    // 4) L2 role-swapped: stripe = A2 (b as j-axis), stream = W2T (o as b-axis).
    //    yp[16][512(b)][512(o)]; grid 4(b) x 8(o) x 16(z), KPER=64 -> 512 blocks.
    morphoS<512, 64><<<dim3(4, 8, 16), 256, 0, stream>>>(
        ws + WS_W2T, ws + WS_A2, ws + WS_YP);

    // 5) combine 16 partials -> d_out[b][o] (no transpose, pre-relu'd)
    combineY2<<<256, 256, 0, stream>>>(ws + WS_YP, out);
}